// Round 8
// baseline (8205.827 us; speedup 1.0000x reference)
//
#include <hip/hip_runtime.h>
#include <hip/hip_bf16.h>

// RecurrentAE on MI355X — round 12 (= round 11 + LDS alignment fix).
//  - r11 bug: sWl[64][514]/sWx[64][130] -> row strides 1028B/260B, NOT 16B multiples ->
//    misaligned ds_*_b128 (undefined). FIX: sWl[64][544] (1088B = 68x16; 272 dwords = 16
//    mod 32 banks -> free 2-way), sWx[64][136] (272B = 17x16).
//  - Theory (unchanged): LLC BW on the h broadcast binds; traffic = #colgroups x 256KB.
//    64 gate WGs x 64 cols (16 units) -> 17 MB/step (halved vs r10).
//  - Per gate WG: 8 waves = rowsplit4 x Ksplit2; each wave 2 col-tiles (A-frag reuse x2),
//    32 kfrags; B hybrid: 16 kfrags/tile in VGPRs (loaded once) + 16 from LDS.
//    Partials sG[2] reduced in gate math. Out: 4 WGs x 32 fcols, same split.
//  - Keep r10: transposed h [kgroup][row][8], no invalidates, single-hop all-poll barrier,
//    LDG16 sc0 sc1 + register-tied vmcnt + sched_barrier, write-through h stores.

#define B_ 128
#define S_ 512
#define F_ 128
#define L_ 1024
#define NWG_E 64
#define NWG_D 68           // 64 gate WGs + 4 out WGs

typedef __bf16 bf16x8 __attribute__((ext_vector_type(8)));
typedef float  f32x4  __attribute__((ext_vector_type(4)));
typedef float  f32x16 __attribute__((ext_vector_type(16)));
typedef int    i32x4  __attribute__((ext_vector_type(4)));
typedef unsigned long long u64;

union pk2 { unsigned u; __bf16 h[2]; };

#define MFMA32(a, b, c) __builtin_amdgcn_mfma_f32_32x32x16_bf16(a, b, c, 0, 0, 0)
#define Z16 f32x16{0.f,0.f,0.f,0.f,0.f,0.f,0.f,0.f,0.f,0.f,0.f,0.f,0.f,0.f,0.f,0.f}

// uncached (LLC-direct) 16B load — plain vector load, fully pipelined
#define LDG16(dst, p) asm volatile("global_load_dwordx4 %0, %1, off sc0 sc1" : "=v"(dst) : "v"(p))
#define VMWAIT16(a) asm volatile("s_waitcnt vmcnt(0)" \
    : "+v"(a[0]),"+v"(a[1]),"+v"(a[2]),"+v"(a[3]),"+v"(a[4]),"+v"(a[5]),"+v"(a[6]),"+v"(a[7]), \
      "+v"(a[8]),"+v"(a[9]),"+v"(a[10]),"+v"(a[11]),"+v"(a[12]),"+v"(a[13]),"+v"(a[14]),"+v"(a[15]) \
    :: "memory")
#define SB0() __builtin_amdgcn_sched_barrier(0)

// ---------------- workspace layout (bytes) ----------------
#define O_H0   0                          // bf16 [128 kgrp][128 row][8 col]
#define O_H1   (256*1024)
#define O_H32  (512*1024)                 // f32  [128][1024]
#define O_CTR  (1024*1024)                // sync: enc @ +0, dec @ +4096
#define O_ZERO_END (1024*1024 + 8192)
#define O_XB   O_ZERO_END                 // bf16 [128][512][128] = 16777216
#define O_WEH  (O_XB  + 16777216)         // bf16 [64][64][1024]  = 8388608
#define O_WEX  (O_WEH + 8388608)          // bf16 [64][64][128]   = 1048576
#define O_BE   (O_WEX + 1048576)          // f32  [64][64]        = 16384
#define O_WD   (O_BE  + 16384)            // bf16 [64][64][1024]  = 8388608
#define O_BD   (O_WD  + 8388608)          // f32  [64][64]        = 16384
#define O_WC   (O_BD  + 16384)            // bf16 [3072][1024]    = 6291456
#define O_WOB  (O_WC  + 6291456)          // bf16 [128][1024]     = 262144

// ---------------- prep kernels ----------------

__global__ void k_xcvt(const float* __restrict__ x, __bf16* __restrict__ xb, int n) {
    int i = blockIdx.x * 256 + threadIdx.x;
    int stride = gridDim.x * 256;
    for (; i < n; i += stride) xb[i] = (__bf16)x[i];
}

__global__ void k_woutb(const float* __restrict__ Wout, __bf16* __restrict__ Wob, int n) {
    int i = blockIdx.x * 256 + threadIdx.x;
    if (i < n) Wob[i] = (__bf16)Wout[i];
}

// encoder pack: 64 cols/WG (16 units), 4 per unit {r, z, n_i, n_h}
__global__ void k_pack_enc(const float* __restrict__ Wih, const float* __restrict__ Whh,
                           const float* __restrict__ bih, const float* __restrict__ bhh,
                           __bf16* __restrict__ Weh, __bf16* __restrict__ Wex,
                           float* __restrict__ be) {
    int g = blockIdx.x, tid = threadIdx.x;
    for (int i = tid; i < 64 * 1024; i += 256) {
        int c = i >> 10, k = i & 1023;
        int u = g * 16 + (c >> 2), gate = c & 3;
        float v = 0.f;
        if (gate == 0)      v = Whh[(size_t)u * 1024 + k];
        else if (gate == 1) v = Whh[(size_t)(1024 + u) * 1024 + k];
        else if (gate == 3) v = Whh[(size_t)(2048 + u) * 1024 + k];
        Weh[((size_t)g * 64 + c) * 1024 + k] = (__bf16)v;
    }
    for (int i = tid; i < 64 * 128; i += 256) {
        int c = i >> 7, k = i & 127;
        int u = g * 16 + (c >> 2), gate = c & 3;
        float v = 0.f;
        if (gate == 0)      v = Wih[(size_t)u * 128 + k];
        else if (gate == 1) v = Wih[(size_t)(1024 + u) * 128 + k];
        else if (gate == 2) v = Wih[(size_t)(2048 + u) * 128 + k];
        Wex[((size_t)g * 64 + c) * 128 + k] = (__bf16)v;
    }
    if (tid < 64) {
        int c = tid, u = g * 16 + (c >> 2), gate = c & 3;
        float v;
        if (gate == 0)      v = bih[u] + bhh[u];
        else if (gate == 1) v = bih[1024 + u] + bhh[1024 + u];
        else if (gate == 2) v = bih[2048 + u];
        else                v = bhh[2048 + u];
        be[g * 64 + c] = v;
    }
}

// W_comb = W_ih_d @ W_out
__global__ void k_wcomb(const float* __restrict__ Wihd, const float* __restrict__ Wout,
                        __bf16* __restrict__ Wc) {
    __shared__ float a[8][128];
    int r0 = blockIdx.x * 8, tid = threadIdx.x;
    for (int i = tid; i < 8 * 128; i += 256)
        a[i >> 7][i & 127] = Wihd[(size_t)(r0 + (i >> 7)) * 128 + (i & 127)];
    __syncthreads();
    for (int j = tid; j < 1024; j += 256) {
        float acc[8] = {0, 0, 0, 0, 0, 0, 0, 0};
        for (int f = 0; f < 128; ++f) {
            float w = Wout[(size_t)f * 1024 + j];
#pragma unroll
            for (int r = 0; r < 8; ++r) acc[r] += a[r][f] * w;
        }
        for (int r = 0; r < 8; ++r) Wc[(size_t)(r0 + r) * 1024 + j] = (__bf16)acc[r];
    }
}

// decoder pack: 64 cols/WG {r:Whh+Wc, z:Whh+Wc, n_i:Wc, n_h:Whh}
__global__ void k_pack_dec(const float* __restrict__ Whhd, const __bf16* __restrict__ Wc,
                           const float* __restrict__ Wihd,
                           const float* __restrict__ bihd, const float* __restrict__ bhhd,
                           const float* __restrict__ bout,
                           __bf16* __restrict__ Wd, float* __restrict__ bd) {
    int g = blockIdx.x, tid = threadIdx.x;
    for (int i = tid; i < 64 * 1024; i += 256) {
        int c = i >> 10, k = i & 1023;
        int u = g * 16 + (c >> 2), gate = c & 3;
        float v;
        if (gate == 0)      v = Whhd[(size_t)u * 1024 + k] + (float)Wc[(size_t)u * 1024 + k];
        else if (gate == 1) v = Whhd[(size_t)(1024 + u) * 1024 + k] + (float)Wc[(size_t)(1024 + u) * 1024 + k];
        else if (gate == 2) v = (float)Wc[(size_t)(2048 + u) * 1024 + k];
        else                v = Whhd[(size_t)(2048 + u) * 1024 + k];
        Wd[((size_t)g * 64 + c) * 1024 + k] = (__bf16)v;
    }
    if (tid < 64) {
        int c = tid;
        int u = g * 16 + (c >> 2), gate = c & 3;
        int row = (gate == 0) ? u : (gate == 1) ? (1024 + u) : (2048 + u);
        float v;
        if (gate <= 1) {
            float d = 0.f;
            for (int f = 0; f < 128; ++f) d += Wihd[(size_t)row * 128 + f] * bout[f];
            v = d + bihd[row] + bhhd[row];
        } else if (gate == 2) {
            float d = 0.f;
            for (int f = 0; f < 128; ++f) d += Wihd[(size_t)row * 128 + f] * bout[f];
            v = d + bihd[row];
        } else {
            v = bhhd[row];
        }
        bd[g * 64 + c] = v;
    }
}

// ---------------- barrier: 16 counters (128B apart), single-hop all-poll, NO inv ----------

__device__ __forceinline__ void bar_arrive(unsigned* base, int g) {
    if (threadIdx.x == 0)
        __hip_atomic_fetch_add(base + (g & 15) * 32, 1u,
                               __ATOMIC_RELAXED, __HIP_MEMORY_SCOPE_AGENT);
}

__device__ __forceinline__ void bar_wait(unsigned* base, unsigned tgt) {
    if (threadIdx.x == 0) {
        for (;;) {
            unsigned sum = 0;
#pragma unroll
            for (int j = 0; j < 16; ++j)
                sum += __hip_atomic_load(base + j * 32, __ATOMIC_RELAXED, __HIP_MEMORY_SCOPE_AGENT);
            if (sum >= tgt) break;
            __builtin_amdgcn_s_sleep(1);
        }
    }
    __syncthreads();
}

// ---------------- encoder: 64 WGs x 64 cols ----------------
__global__ __launch_bounds__(512, 2) void k_enc(
    const __bf16* __restrict__ xb, const __bf16* __restrict__ Weh,
    const __bf16* __restrict__ Wex, const float* __restrict__ be,
    __bf16* __restrict__ h0, __bf16* __restrict__ h1,
    float* __restrict__ h32, unsigned* __restrict__ ctr) {
    __shared__ __align__(16) __bf16 sWl[64][544];   // LDS kfrags {16..31,48..63}, f'=ks*16+i
    __shared__ __align__(16) __bf16 sWx[64][136];
    __shared__ __align__(16) float sB[64];
    __shared__ __align__(16) float sG[2][128][68];
    const int g = blockIdx.x, tid = threadIdx.x;
    const int lane = tid & 63, wave = tid >> 6;

    for (int i = tid; i < 64 * 64; i += 512) {
        int c = i >> 6, q = i & 63;                  // q = 8-elem quad within 512
        int fp = q >> 1, half = q & 1;
        int kf = (fp >> 4) * 32 + 16 + (fp & 15);
        *(i32x4*)&sWl[c][q * 8] = *(const i32x4*)(Weh + ((size_t)g * 64 + c) * 1024 + kf * 16 + half * 8);
    }
    for (int i = tid; i < 64 * 16; i += 512) {
        int c = i >> 4, q = i & 15;
        *(i32x4*)&sWx[c][q * 8] = *(const i32x4*)(Wex + ((size_t)g * 64 + c) * 128 + q * 8);
    }
    if (tid < 64) sB[tid] = be[g * 64 + tid];
    __syncthreads();

    const int bcol = lane & 31;
    const int koff = (lane >> 5) * 8;
    const int rs = wave & 3, ks = wave >> 2;         // rowsplit 4 x Ksplit 2
    const int arow = rs * 32 + bcol;

    // reg-resident B: kfrags ks*32 + 0..15, both col tiles (loaded once)
    bf16x8 br0[16], br1[16];
#pragma unroll
    for (int i = 0; i < 16; ++i) {
        int kf = ks * 32 + i;
        br0[i] = *(const bf16x8*)(Weh + ((size_t)g * 64 + bcol) * 1024 + kf * 16 + koff);
        br1[i] = *(const bf16x8*)(Weh + ((size_t)g * 64 + 32 + bcol) * 1024 + kf * 16 + koff);
    }

    const int erow = tid >> 2, p4 = tid & 3;         // 4 units per thread
    float hst[4] = {0.f, 0.f, 0.f, 0.f};

    // x-part of step 0 (all waves; xfrags ks*4..+3)
    f32x16 ax0 = Z16, ax1 = Z16;
    {
        const __bf16* xr = xb + (size_t)arow * 65536;
#pragma unroll
        for (int i = 0; i < 4; ++i) {
            int kf = ks * 4 + i;
            bf16x8 a = *(const bf16x8*)(xr + kf * 16 + koff);
            ax0 = MFMA32(a, *(const bf16x8*)(&sWx[bcol][kf * 16 + koff]), ax0);
            ax1 = MFMA32(a, *(const bf16x8*)(&sWx[32 + bcol][kf * 16 + koff]), ax1);
        }
    }

    for (int s = 0; s < 512; ++s) {
        const __bf16* hcur = (s & 1) ? h1 : h0;
        __bf16* hnxt = (s & 1) ? h0 : h1;
        {
            f32x16 a0 = ax0, a1 = ax1;
            // A: kfrag = ks*32+i -> kgroup = kfrag*2 + (koff>>3); stride per i = 2048 elems
            const __bf16* hr = hcur + ((size_t)(ks * 64 + (koff >> 3)) << 10) + arow * 8;
            bf16x8 af[16];
#pragma unroll
            for (int i = 0; i < 16; ++i) LDG16(af[i], hr + i * 2048);
            VMWAIT16(af); SB0();
#pragma unroll
            for (int i = 0; i < 16; ++i) {
                a0 = MFMA32(af[i], br0[i], a0);
                a1 = MFMA32(af[i], br1[i], a1);
                LDG16(af[i], hr + (16 + i) * 2048);
            }
            VMWAIT16(af); SB0();
#pragma unroll
            for (int i = 0; i < 16; ++i) {
                int fp = ks * 16 + i;
                a0 = MFMA32(af[i], *(const bf16x8*)(&sWl[bcol][fp * 16 + koff]), a0);
                a1 = MFMA32(af[i], *(const bf16x8*)(&sWl[32 + bcol][fp * 16 + koff]), a1);
            }
            int rb = rs * 32 + 4 * (lane >> 5);
#pragma unroll
            for (int r = 0; r < 16; ++r) {
                int rw = rb + (r & 3) + 8 * (r >> 2);
                sG[ks][rw][bcol] = a0[r];
                sG[ks][rw][32 + bcol] = a1[r];
            }
        }
        __syncthreads();
        {
#pragma unroll
            for (int uu = 0; uu < 4; ++uu) {
                int c0 = (p4 * 4 + uu) * 4;
                f32x4 v = *(const f32x4*)&sG[0][erow][c0] + *(const f32x4*)&sG[1][erow][c0];
                float r = 1.f / (1.f + __expf(-(v[0] + sB[c0 + 0])));
                float z = 1.f / (1.f + __expf(-(v[1] + sB[c0 + 1])));
                float n = tanhf(v[2] + sB[c0 + 2] + r * (v[3] + sB[c0 + 3]));
                hst[uu] = (1.f - z) * n + z * hst[uu];
            }
#pragma unroll
            for (int j = 0; j < 2; ++j) {
                int lu = p4 * 4 + 2 * j;
                pk2 p; p.h[0] = (__bf16)hst[2 * j]; p.h[1] = (__bf16)hst[2 * j + 1];
                int hidx2 = (g * 2 + (lu >> 3)) * 512 + erow * 4 + ((lu >> 1) & 3);
                __hip_atomic_store((unsigned*)hnxt + hidx2, p.u, __ATOMIC_RELAXED, __HIP_MEMORY_SCOPE_AGENT);
            }
            if (s == 511) {
                f32x4 o; o[0] = hst[0]; o[1] = hst[1]; o[2] = hst[2]; o[3] = hst[3];
                *(f32x4*)(h32 + erow * 1024 + g * 16 + p4 * 4) = o;
            }
        }
        if (s < 511) {
            __syncthreads();              // drains write-through h stores
            bar_arrive(ctr, g);
            // x-part of step s+1 overlapped with the poll (x cached, L2 warm)
            ax0 = Z16; ax1 = Z16;
            const __bf16* xr = xb + (size_t)arow * 65536 + (size_t)(s + 1) * 128;
#pragma unroll
            for (int i = 0; i < 4; ++i) {
                int kf = ks * 4 + i;
                bf16x8 a = *(const bf16x8*)(xr + kf * 16 + koff);
                ax0 = MFMA32(a, *(const bf16x8*)(&sWx[bcol][kf * 16 + koff]), ax0);
                ax1 = MFMA32(a, *(const bf16x8*)(&sWx[32 + bcol][kf * 16 + koff]), ax1);
            }
            bar_wait(ctr, (unsigned)(s + 1) * NWG_E);
        }
    }
}

// ---------------- decoder ----------------
// g < 64 : gate WG (64 cols, 16 units; rowsplit4 x Ksplit2)
// g >= 64: out WG  (32 f-cols; rowsplit4 x Ksplit2; plain vector out stores)
__global__ __launch_bounds__(512, 2) void k_dec(
    const __bf16* __restrict__ Wd, const float* __restrict__ bd,
    const __bf16* __restrict__ Wob, const float* __restrict__ bout,
    __bf16* __restrict__ h0, __bf16* __restrict__ h1,
    const float* __restrict__ h32, float* __restrict__ out,
    unsigned* __restrict__ ctr) {
    __shared__ __align__(16) __bf16 sWl[64][544];
    __shared__ __align__(16) float sB[64];
    __shared__ __align__(16) float sG[2][128][68];
    const int g = blockIdx.x, tid = threadIdx.x;
    const int lane = tid & 63, wave = tid >> 6;
    const bool gwg = (g < 64);

    const int bcol = lane & 31;
    const int koff = (lane >> 5) * 8;
    const int rs = wave & 3, ks = wave >> 2;
    const int arow = rs * 32 + bcol;

    if (gwg) {
        for (int i = tid; i < 64 * 64; i += 512) {
            int c = i >> 6, q = i & 63;
            int fp = q >> 1, half = q & 1;
            int kf = (fp >> 4) * 32 + 16 + (fp & 15);
            *(i32x4*)&sWl[c][q * 8] = *(const i32x4*)(Wd + ((size_t)g * 64 + c) * 1024 + kf * 16 + half * 8);
        }
        if (tid < 64) sB[tid] = bd[g * 64 + tid];
        __syncthreads();

        bf16x8 br0[16], br1[16];
#pragma unroll
        for (int i = 0; i < 16; ++i) {
            int kf = ks * 32 + i;
            br0[i] = *(const bf16x8*)(Wd + ((size_t)g * 64 + bcol) * 1024 + kf * 16 + koff);
            br1[i] = *(const bf16x8*)(Wd + ((size_t)g * 64 + 32 + bcol) * 1024 + kf * 16 + koff);
        }

        const int erow = tid >> 2, p4 = tid & 3;
        float hst[4];
        {
            f32x4 hi = *(const f32x4*)(h32 + erow * 1024 + g * 16 + p4 * 4);
            hst[0] = hi[0]; hst[1] = hi[1]; hst[2] = hi[2]; hst[3] = hi[3];
        }

        for (int s = 0; s < 512; ++s) {
            const __bf16* hcur = (s & 1) ? h1 : h0;
            __bf16* hnxt = (s & 1) ? h0 : h1;
            {
                f32x16 a0 = Z16, a1 = Z16;
                const __bf16* hr = hcur + ((size_t)(ks * 64 + (koff >> 3)) << 10) + arow * 8;
                bf16x8 af[16];
#pragma unroll
                for (int i = 0; i < 16; ++i) LDG16(af[i], hr + i * 2048);
                VMWAIT16(af); SB0();
#pragma unroll
                for (int i = 0; i < 16; ++i) {
                    a0 = MFMA32(af[i], br0[i], a0);
                    a1 = MFMA32(af[i], br1[i], a1);
                    LDG16(af[i], hr + (16 + i) * 2048);
                }
                VMWAIT16(af); SB0();
#pragma unroll
                for (int i = 0; i < 16; ++i) {
                    int fp = ks * 16 + i;
                    a0 = MFMA32(af[i], *(const bf16x8*)(&sWl[bcol][fp * 16 + koff]), a0);
                    a1 = MFMA32(af[i], *(const bf16x8*)(&sWl[32 + bcol][fp * 16 + koff]), a1);
                }
                int rb = rs * 32 + 4 * (lane >> 5);
#pragma unroll
                for (int r = 0; r < 16; ++r) {
                    int rw = rb + (r & 3) + 8 * (r >> 2);
                    sG[ks][rw][bcol] = a0[r];
                    sG[ks][rw][32 + bcol] = a1[r];
                }
            }
            __syncthreads();
            {
                const int erow2 = erow, p42 = p4;
#pragma unroll
                for (int uu = 0; uu < 4; ++uu) {
                    int c0 = (p42 * 4 + uu) * 4;
                    f32x4 v = *(const f32x4*)&sG[0][erow2][c0] + *(const f32x4*)&sG[1][erow2][c0];
                    float r = 1.f / (1.f + __expf(-(v[0] + sB[c0 + 0])));
                    float z = 1.f / (1.f + __expf(-(v[1] + sB[c0 + 1])));
                    float n = tanhf(v[2] + sB[c0 + 2] + r * (v[3] + sB[c0 + 3]));
                    hst[uu] = (1.f - z) * n + z * hst[uu];
                }
#pragma unroll
                for (int j = 0; j < 2; ++j) {
                    int lu = p42 * 4 + 2 * j;
                    pk2 p; p.h[0] = (__bf16)hst[2 * j]; p.h[1] = (__bf16)hst[2 * j + 1];
                    int hidx2 = (g * 2 + (lu >> 3)) * 512 + erow2 * 4 + ((lu >> 1) & 3);
                    __hip_atomic_store((unsigned*)hnxt + hidx2, p.u, __ATOMIC_RELAXED, __HIP_MEMORY_SCOPE_AGENT);
                }
            }
            __syncthreads();              // drains write-through h stores
            bar_arrive(ctr, g);
            if (s < 511) bar_wait(ctr, (unsigned)(s + 1) * NWG_D);
        }
    } else {
        // out WG: go in 0..3, fbase = go*32; iteration s computes out col 512-s (s=1..512)
        const int go = g - 64;
        const int fbase = go * 32;
        for (int i = tid; i < 32 * 64; i += 512) {
            int c = i >> 6, q = i & 63;
            int fp = q >> 1, half = q & 1;
            int kf = (fp >> 4) * 32 + 16 + (fp & 15);
            *(i32x4*)&sWl[c][q * 8] = *(const i32x4*)(Wob + ((size_t)(fbase + c)) * 1024 + kf * 16 + half * 8);
        }
        if (tid < 32) sB[tid] = bout[fbase + tid];
        __syncthreads();

        bf16x8 br[16];
#pragma unroll
        for (int i = 0; i < 16; ++i) {
            int kf = ks * 32 + i;
            br[i] = *(const bf16x8*)(Wob + ((size_t)(fbase + bcol)) * 1024 + kf * 16 + koff);
        }

        for (int s = 0; s <= 512; ++s) {
            const __bf16* hcur = (s & 1) ? h1 : h0;
            if (s >= 1) {
                f32x16 a0 = Z16;
                const __bf16* hr = hcur + ((size_t)(ks * 64 + (koff >> 3)) << 10) + arow * 8;
                bf16x8 af[16];
#pragma unroll
                for (int i = 0; i < 16; ++i) LDG16(af[i], hr + i * 2048);
                VMWAIT16(af); SB0();
#pragma unroll
                for (int i = 0; i < 16; ++i) {
                    a0 = MFMA32(af[i], br[i], a0);
                    LDG16(af[i], hr + (16 + i) * 2048);
                }
                VMWAIT16(af); SB0();
#pragma unroll
                for (int i = 0; i < 16; ++i) {
                    int fp = ks * 16 + i;
                    a0 = MFMA32(af[i], *(const bf16x8*)(&sWl[bcol][fp * 16 + koff]), a0);
                }
                int rb = rs * 32 + 4 * (lane >> 5);
#pragma unroll
                for (int r = 0; r < 16; ++r)
                    sG[ks][rb + (r & 3) + 8 * (r >> 2)][bcol] = a0[r];
            }
            __syncthreads();              // partials visible (and h consumed)
            if (s < 512) bar_arrive(ctr, g);
            if (s >= 1) {
                // reduce 2 partials + bias; plain vector stores, overlapped with the poll
                int row = tid >> 2, q = tid & 3;
#pragma unroll
                for (int part = 0; part < 2; ++part) {
                    int c0 = q * 4 + part * 16;
                    f32x4 v = *(const f32x4*)&sG[0][row][c0] + *(const f32x4*)&sG[1][row][c0]
                            + *(const f32x4*)&sB[c0];
                    *(f32x4*)(out + (size_t)row * 65536 + (size_t)(512 - s) * 128 + fbase + c0) = v;
                }
            }
            if (s < 512) bar_wait(ctr, (unsigned)(s + 1) * NWG_D);
        }
    }
}

// ---------------- launch ----------------
extern "C" void kernel_launch(void* const* d_in, const int* in_sizes, int n_in,
                              void* d_out, int out_size, void* d_ws, size_t ws_size,
                              hipStream_t stream) {
    (void)in_sizes; (void)n_in; (void)out_size; (void)ws_size;
    const float* x    = (const float*)d_in[0];
    const float* Wihe = (const float*)d_in[1];
    const float* Whhe = (const float*)d_in[2];
    const float* bihe = (const float*)d_in[3];
    const float* bhhe = (const float*)d_in[4];
    const float* Wihd = (const float*)d_in[5];
    const float* Whhd = (const float*)d_in[6];
    const float* bihd = (const float*)d_in[7];
    const float* bhhd = (const float*)d_in[8];
    const float* Wout = (const float*)d_in[9];
    const float* bout = (const float*)d_in[10];

    char* ws = (char*)d_ws;
    __bf16*   h0  = (__bf16*)(ws + O_H0);
    __bf16*   h1  = (__bf16*)(ws + O_H1);
    float*    h32 = (float*)(ws + O_H32);
    unsigned* ctr = (unsigned*)(ws + O_CTR);
    __bf16*   xbf = (__bf16*)(ws + O_XB);
    __bf16*   Weh = (__bf16*)(ws + O_WEH);
    __bf16*   Wex = (__bf16*)(ws + O_WEX);
    float*    be  = (float*)(ws + O_BE);
    __bf16*   Wd  = (__bf16*)(ws + O_WD);
    float*    bd  = (float*)(ws + O_BD);
    __bf16*   Wc  = (__bf16*)(ws + O_WC);
    __bf16*   Wob = (__bf16*)(ws + O_WOB);

    hipMemsetAsync(ws, 0, O_ZERO_END, stream);   // h0/h1/h32 + both sync blocks

    k_xcvt<<<4096, 256, 0, stream>>>(x, xbf, B_ * S_ * F_);
    k_pack_enc<<<NWG_E, 256, 0, stream>>>(Wihe, Whhe, bihe, bhhe, Weh, Wex, be);
    k_wcomb<<<384, 256, 0, stream>>>(Wihd, Wout, Wc);
    k_pack_dec<<<NWG_E, 256, 0, stream>>>(Whhd, Wc, Wihd, bihd, bhhd, bout, Wd, bd);
    k_woutb<<<512, 256, 0, stream>>>(Wout, Wob, F_ * L_);

    k_enc<<<NWG_E, 512, 0, stream>>>(xbf, Weh, Wex, be, h0, h1, h32, ctr);
    k_dec<<<NWG_D, 512, 0, stream>>>(Wd, bd, Wob, bout, h0, h1, h32, (float*)d_out,
                                     ctr + 1024);
}

// Round 9
// 5144.055 us; speedup vs baseline: 1.5952x; 1.5952x over previous
//
#include <hip/hip_runtime.h>
#include <hip/hip_bf16.h>

// RecurrentAE on MI355X — round 13.
//  - r12 post-mortem: halving colgroups did NOT help (per-WG ingest unchanged at 256KB,
//    16-way LDS bank conflict from 544-elem stride, half the CUs). Aggregate-LLC-BW
//    theory dead; binding term = per-WG ingest + load->MFMA chain.
//  - NEW: 256 homogeneous WGs = 2 rowgroups(64 rows) x 128 colgroups(32 cols).
//    Per-WG ingest 128 KB/step (8 waves = rowsplit2 x ksplit4, 16 frags each, unique);
//    ONE 16-load batch -> one vmcnt -> 16 MFMA (r10 had 2 serialized batches).
//  - Out-WGs eliminated (grid must stay <=256 for co-residency): decoder WG (rg,cg)
//    computes out col f=cg as VALU dot on its own h frags (wf[16] regs), shfl+LDS
//    reduce, stored in the barrier window; extra s=512 iteration emits out col 0.
//  - Keep r10: transposed h [kgroup][row][8], no invalidates, single-hop all-poll
//    barrier, LDG16 sc0 sc1 + register-tied vmcnt + sched_barrier, write-through
//    h stores, sW stride 1032 (516 dw = 4 mod 32, known 4-way).

#define B_ 128
#define S_ 512
#define F_ 128
#define L_ 1024
#define NWG 256

typedef __bf16 bf16x8 __attribute__((ext_vector_type(8)));
typedef float  f32x4  __attribute__((ext_vector_type(4)));
typedef float  f32x16 __attribute__((ext_vector_type(16)));
typedef int    i32x4  __attribute__((ext_vector_type(4)));

union pk2 { unsigned u; __bf16 h[2]; };
union fu  { float f; unsigned u; };

#define MFMA32(a, b, c) __builtin_amdgcn_mfma_f32_32x32x16_bf16(a, b, c, 0, 0, 0)
#define Z16 f32x16{0.f,0.f,0.f,0.f,0.f,0.f,0.f,0.f,0.f,0.f,0.f,0.f,0.f,0.f,0.f,0.f}

// uncached (LLC-direct) 16B load — plain vector load, fully pipelined
#define LDG16(dst, p) asm volatile("global_load_dwordx4 %0, %1, off sc0 sc1" : "=v"(dst) : "v"(p))
#define VMWAIT16(a) asm volatile("s_waitcnt vmcnt(0)" \
    : "+v"(a[0]),"+v"(a[1]),"+v"(a[2]),"+v"(a[3]),"+v"(a[4]),"+v"(a[5]),"+v"(a[6]),"+v"(a[7]), \
      "+v"(a[8]),"+v"(a[9]),"+v"(a[10]),"+v"(a[11]),"+v"(a[12]),"+v"(a[13]),"+v"(a[14]),"+v"(a[15]) \
    :: "memory")
#define SB0() __builtin_amdgcn_sched_barrier(0)

// ---------------- workspace layout (bytes) — r10 map ----------------
#define O_H0   0                          // bf16 [128 kgrp][128 row][8 col]
#define O_H1   (256*1024)
#define O_H32  (512*1024)                 // f32  [128][1024]
#define O_CTR  (1024*1024)                // sync: enc @ +0, dec @ +4096
#define O_ZERO_END (1024*1024 + 8192)
#define O_XB   O_ZERO_END                 // bf16 [128][512][128] = 16777216
#define O_WEH  (O_XB  + 16777216)         // bf16 [128][32][1024] = 8388608
#define O_WEX  (O_WEH + 8388608)          // bf16 [128][32][128]  = 1048576
#define O_BE   (O_WEX + 1048576)          // f32  [128][32]       = 16384
#define O_WD   (O_BE  + 16384)            // bf16 [128][32][1024] = 8388608
#define O_BD   (O_WD  + 8388608)          // f32  [128][32]       = 16384
#define O_WC   (O_BD  + 16384)            // bf16 [3072][1024]    = 6291456
#define O_WOB  (O_WC  + 6291456)          // bf16 [128][1024]     = 262144

// ---------------- prep kernels (r10 versions, unchanged) ----------------

__global__ void k_xcvt(const float* __restrict__ x, __bf16* __restrict__ xb, int n) {
    int i = blockIdx.x * 256 + threadIdx.x;
    int stride = gridDim.x * 256;
    for (; i < n; i += stride) xb[i] = (__bf16)x[i];
}

__global__ void k_woutb(const float* __restrict__ Wout, __bf16* __restrict__ Wob, int n) {
    int i = blockIdx.x * 256 + threadIdx.x;
    if (i < n) Wob[i] = (__bf16)Wout[i];
}

// encoder pack: 32 cols/colgroup, 4 per unit {r, z, n_i, n_h}
__global__ void k_pack_enc(const float* __restrict__ Wih, const float* __restrict__ Whh,
                           const float* __restrict__ bih, const float* __restrict__ bhh,
                           __bf16* __restrict__ Weh, __bf16* __restrict__ Wex,
                           float* __restrict__ be) {
    int g = blockIdx.x, tid = threadIdx.x;
    for (int i = tid; i < 32 * 1024; i += 256) {
        int c = i >> 10, k = i & 1023;
        int u = g * 8 + (c >> 2), gate = c & 3;
        float v = 0.f;
        if (gate == 0)      v = Whh[(size_t)u * 1024 + k];
        else if (gate == 1) v = Whh[(size_t)(1024 + u) * 1024 + k];
        else if (gate == 3) v = Whh[(size_t)(2048 + u) * 1024 + k];
        Weh[((size_t)g * 32 + c) * 1024 + k] = (__bf16)v;
    }
    for (int i = tid; i < 32 * 128; i += 256) {
        int c = i >> 7, k = i & 127;
        int u = g * 8 + (c >> 2), gate = c & 3;
        float v = 0.f;
        if (gate == 0)      v = Wih[(size_t)u * 128 + k];
        else if (gate == 1) v = Wih[(size_t)(1024 + u) * 128 + k];
        else if (gate == 2) v = Wih[(size_t)(2048 + u) * 128 + k];
        Wex[((size_t)g * 32 + c) * 128 + k] = (__bf16)v;
    }
    if (tid < 32) {
        int c = tid, u = g * 8 + (c >> 2), gate = c & 3;
        float v;
        if (gate == 0)      v = bih[u] + bhh[u];
        else if (gate == 1) v = bih[1024 + u] + bhh[1024 + u];
        else if (gate == 2) v = bih[2048 + u];
        else                v = bhh[2048 + u];
        be[g * 32 + c] = v;
    }
}

// W_comb = W_ih_d @ W_out
__global__ void k_wcomb(const float* __restrict__ Wihd, const float* __restrict__ Wout,
                        __bf16* __restrict__ Wc) {
    __shared__ float a[8][128];
    int r0 = blockIdx.x * 8, tid = threadIdx.x;
    for (int i = tid; i < 8 * 128; i += 256)
        a[i >> 7][i & 127] = Wihd[(size_t)(r0 + (i >> 7)) * 128 + (i & 127)];
    __syncthreads();
    for (int j = tid; j < 1024; j += 256) {
        float acc[8] = {0, 0, 0, 0, 0, 0, 0, 0};
        for (int f = 0; f < 128; ++f) {
            float w = Wout[(size_t)f * 1024 + j];
#pragma unroll
            for (int r = 0; r < 8; ++r) acc[r] += a[r][f] * w;
        }
        for (int r = 0; r < 8; ++r) Wc[(size_t)(r0 + r) * 1024 + j] = (__bf16)acc[r];
    }
}

// decoder pack: 32 cols/colgroup {r:Whh+Wc, z:Whh+Wc, n_i:Wc, n_h:Whh}
__global__ void k_pack_dec(const float* __restrict__ Whhd, const __bf16* __restrict__ Wc,
                           const float* __restrict__ Wihd,
                           const float* __restrict__ bihd, const float* __restrict__ bhhd,
                           const float* __restrict__ bout,
                           __bf16* __restrict__ Wd, float* __restrict__ bd) {
    int g = blockIdx.x, tid = threadIdx.x;
    for (int i = tid; i < 32 * 1024; i += 256) {
        int c = i >> 10, k = i & 1023;
        int u = g * 8 + (c >> 2), gate = c & 3;
        float v;
        if (gate == 0)      v = Whhd[(size_t)u * 1024 + k] + (float)Wc[(size_t)u * 1024 + k];
        else if (gate == 1) v = Whhd[(size_t)(1024 + u) * 1024 + k] + (float)Wc[(size_t)(1024 + u) * 1024 + k];
        else if (gate == 2) v = (float)Wc[(size_t)(2048 + u) * 1024 + k];
        else                v = Whhd[(size_t)(2048 + u) * 1024 + k];
        Wd[((size_t)g * 32 + c) * 1024 + k] = (__bf16)v;
    }
    if (tid < 32) {
        int c = tid;
        int u = g * 8 + (c >> 2), gate = c & 3;
        int row = (gate == 0) ? u : (gate == 1) ? (1024 + u) : (2048 + u);
        float v;
        if (gate <= 1) {
            float d = 0.f;
            for (int f = 0; f < 128; ++f) d += Wihd[(size_t)row * 128 + f] * bout[f];
            v = d + bihd[row] + bhhd[row];
        } else if (gate == 2) {
            float d = 0.f;
            for (int f = 0; f < 128; ++f) d += Wihd[(size_t)row * 128 + f] * bout[f];
            v = d + bihd[row];
        } else {
            v = bhhd[row];
        }
        bd[g * 32 + c] = v;
    }
}

// ---------------- barrier: 16 counters (128B apart), single-hop all-poll, NO inv ----------

__device__ __forceinline__ void bar_arrive(unsigned* base, int g) {
    if (threadIdx.x == 0)
        __hip_atomic_fetch_add(base + (g & 15) * 32, 1u,
                               __ATOMIC_RELAXED, __HIP_MEMORY_SCOPE_AGENT);
}

__device__ __forceinline__ void bar_wait(unsigned* base, unsigned tgt) {
    if (threadIdx.x == 0) {
        for (;;) {
            unsigned sum = 0;
#pragma unroll
            for (int j = 0; j < 16; ++j)
                sum += __hip_atomic_load(base + j * 32, __ATOMIC_RELAXED, __HIP_MEMORY_SCOPE_AGENT);
            if (sum >= tgt) break;
            __builtin_amdgcn_s_sleep(1);
        }
    }
    __syncthreads();
}

// ---------------- encoder: 256 WGs = 2 rowgroups x 128 colgroups ----------------
__global__ __launch_bounds__(512, 2) void k_enc(
    const __bf16* __restrict__ xb, const __bf16* __restrict__ Weh,
    const __bf16* __restrict__ Wex, const float* __restrict__ be,
    __bf16* __restrict__ h0, __bf16* __restrict__ h1,
    float* __restrict__ h32, unsigned* __restrict__ ctr) {
    __shared__ __align__(16) __bf16 sWh[32][1032];
    __shared__ __align__(16) __bf16 sWx[32][136];
    __shared__ float sB[32];
    __shared__ __align__(16) float sG[4][64][36];
    const int g = blockIdx.x, tid = threadIdx.x;
    const int lane = tid & 63, wave = tid >> 6;
    const int cg = g & 127, rg = g >> 7;

    for (int i = tid; i < 32 * 128; i += 512) {
        int c = i >> 7, k8 = i & 127;
        *(i32x4*)&sWh[c][k8 * 8] = *(const i32x4*)(Weh + ((size_t)cg * 32 + c) * 1024 + k8 * 8);
    }
    for (int i = tid; i < 32 * 16; i += 512) {
        int c = i >> 4, k8 = i & 15;
        *(i32x4*)&sWx[c][k8 * 8] = *(const i32x4*)(Wex + ((size_t)cg * 32 + c) * 128 + k8 * 8);
    }
    if (tid < 32) sB[tid] = be[cg * 32 + tid];
    __syncthreads();

    const int bcol = lane & 31;
    const int koff = (lane >> 5) * 8;
    const int rs = wave & 1, ks = wave >> 1;       // rowsplit2 x ksplit4
    const int grow = rg * 64 + rs * 32 + bcol;     // global batch row (A operand)

    const int lrow = tid >> 3, up = tid & 7;       // gate-math: local row, unit
    const int growg = rg * 64 + lrow;
    float hst = 0.f;

    // x-part of step 0 (frags ks*2, ks*2+1)
    f32x16 accx = Z16;
    {
        const __bf16* xr = xb + (size_t)grow * 65536;
#pragma unroll
        for (int i = 0; i < 2; ++i) {
            int kx = ks * 2 + i;
            bf16x8 a = *(const bf16x8*)(xr + kx * 16 + koff);
            accx = MFMA32(a, *(const bf16x8*)(&sWx[bcol][kx * 16 + koff]), accx);
        }
    }

    for (int s = 0; s < 512; ++s) {
        const __bf16* hcur = (s & 1) ? h1 : h0;
        __bf16* hnxt = (s & 1) ? h0 : h1;
        {
            f32x16 acc = accx;
            // kfrag = ks*16+i -> kgroup = kfrag*2 + (koff>>3); i-stride = 2 kgroups = 2048 elems
            const __bf16* hr = hcur + ((size_t)(ks * 32 + (koff >> 3)) << 10) + grow * 8;
            bf16x8 af[16];
#pragma unroll
            for (int i = 0; i < 16; ++i) LDG16(af[i], hr + i * 2048);
            VMWAIT16(af); SB0();
#pragma unroll
            for (int i = 0; i < 16; ++i)
                acc = MFMA32(af[i], *(const bf16x8*)(&sWh[bcol][(ks * 16 + i) * 16 + koff]), acc);
            int rb = rs * 32 + 4 * (lane >> 5);
#pragma unroll
            for (int r = 0; r < 16; ++r)
                sG[ks][rb + (r & 3) + 8 * (r >> 2)][bcol] = acc[r];
        }
        __syncthreads();
        {
            int c0 = up * 4;
            f32x4 v = *(const f32x4*)&sG[0][lrow][c0] + *(const f32x4*)&sG[1][lrow][c0]
                    + *(const f32x4*)&sG[2][lrow][c0] + *(const f32x4*)&sG[3][lrow][c0];
            float r = 1.f / (1.f + __expf(-(v[0] + sB[c0 + 0])));
            float z = 1.f / (1.f + __expf(-(v[1] + sB[c0 + 1])));
            float n = tanhf(v[2] + sB[c0 + 2] + r * (v[3] + sB[c0 + 3]));
            hst = (1.f - z) * n + z * hst;
            float hnb = __shfl_down(hst, 1);
            if ((up & 1) == 0) {
                pk2 p; p.h[0] = (__bf16)hst; p.h[1] = (__bf16)hnb;
                __hip_atomic_store((unsigned*)hnxt + cg * 512 + growg * 4 + (up >> 1), p.u,
                                   __ATOMIC_RELAXED, __HIP_MEMORY_SCOPE_AGENT);
            }
            if (s == 511) h32[growg * 1024 + cg * 8 + up] = hst;
        }
        if (s < 511) {
            __syncthreads();              // drains write-through h stores
            bar_arrive(ctr, g);
            // overlap x-part of step s+1 (x cached, L2 warm)
            accx = Z16;
            const __bf16* xr = xb + (size_t)grow * 65536 + (size_t)(s + 1) * 128;
#pragma unroll
            for (int i = 0; i < 2; ++i) {
                int kx = ks * 2 + i;
                bf16x8 a = *(const bf16x8*)(xr + kx * 16 + koff);
                accx = MFMA32(a, *(const bf16x8*)(&sWx[bcol][kx * 16 + koff]), accx);
            }
            bar_wait(ctr, (unsigned)(s + 1) * NWG);
        }
    }
}

// ---------------- decoder: 256 WGs; out col f=cg computed in-gate ----------------
__global__ __launch_bounds__(512, 2) void k_dec(
    const __bf16* __restrict__ Wd, const float* __restrict__ bd,
    const __bf16* __restrict__ Wob, const float* __restrict__ bout,
    __bf16* __restrict__ h0, __bf16* __restrict__ h1,
    const float* __restrict__ h32, float* __restrict__ out,
    unsigned* __restrict__ ctr) {
    __shared__ __align__(16) __bf16 sW[32][1032];
    __shared__ float sB[32];
    __shared__ __align__(16) float sG[4][64][36];
    __shared__ float sOd[2][32][4];
    const int g = blockIdx.x, tid = threadIdx.x;
    const int lane = tid & 63, wave = tid >> 6;
    const int cg = g & 127, rg = g >> 7;

    for (int i = tid; i < 32 * 128; i += 512) {
        int c = i >> 7, k8 = i & 127;
        *(i32x4*)&sW[c][k8 * 8] = *(const i32x4*)(Wd + ((size_t)cg * 32 + c) * 1024 + k8 * 8);
    }
    if (tid < 32) sB[tid] = bd[cg * 32 + tid];
    __syncthreads();

    const int bcol = lane & 31;
    const int koff = (lane >> 5) * 8;
    const int rs = wave & 1, ks = wave >> 1;
    const int grow = rg * 64 + rs * 32 + bcol;

    const int lrow = tid >> 3, up = tid & 7;
    const int growg = rg * 64 + lrow;
    float hst = h32[growg * 1024 + cg * 8 + up];
    const float ob = bout[cg];

    // W_out col cg, this lane's K-subset (matches af frag layout)
    bf16x8 wf[16];
#pragma unroll
    for (int i = 0; i < 16; ++i)
        wf[i] = *(const bf16x8*)(Wob + (size_t)cg * 1024 + (ks * 16 + i) * 16 + koff);

    for (int s = 0; s <= 512; ++s) {
        const __bf16* hcur = (s & 1) ? h1 : h0;
        __bf16* hnxt = (s & 1) ? h0 : h1;
        bf16x8 af[16];
        {
            const __bf16* hr = hcur + ((size_t)(ks * 32 + (koff >> 3)) << 10) + grow * 8;
#pragma unroll
            for (int i = 0; i < 16; ++i) LDG16(af[i], hr + i * 2048);
            VMWAIT16(af); SB0();
        }
        if (s < 512) {
            f32x16 acc = Z16;
#pragma unroll
            for (int i = 0; i < 16; ++i)
                acc = MFMA32(af[i], *(const bf16x8*)(&sW[bcol][(ks * 16 + i) * 16 + koff]), acc);
            int rb = rs * 32 + 4 * (lane >> 5);
#pragma unroll
            for (int r = 0; r < 16; ++r)
                sG[ks][rb + (r & 3) + 8 * (r >> 2)][bcol] = acc[r];
        }
        if (s >= 1) {
            // out partial: dot(h_s[grow], Wout[cg]) over this lane's K-subset
            float pd = 0.f;
#pragma unroll
            for (int i = 0; i < 16; ++i)
#pragma unroll
                for (int j = 0; j < 8; ++j)
                    pd += (float)af[i][j] * (float)wf[i][j];
            pd += __shfl_xor(pd, 32);     // merge koff halves (same row)
            if (lane < 32) sOd[rs][bcol][ks] = pd;
        }
        __syncthreads();
        if (s < 512) {
            int c0 = up * 4;
            f32x4 v = *(const f32x4*)&sG[0][lrow][c0] + *(const f32x4*)&sG[1][lrow][c0]
                    + *(const f32x4*)&sG[2][lrow][c0] + *(const f32x4*)&sG[3][lrow][c0];
            float r = 1.f / (1.f + __expf(-(v[0] + sB[c0 + 0])));
            float z = 1.f / (1.f + __expf(-(v[1] + sB[c0 + 1])));
            float n = tanhf(v[2] + sB[c0 + 2] + r * (v[3] + sB[c0 + 3]));
            hst = (1.f - z) * n + z * hst;
            float hnb = __shfl_down(hst, 1);
            if ((up & 1) == 0) {
                pk2 p; p.h[0] = (__bf16)hst; p.h[1] = (__bf16)hnb;
                __hip_atomic_store((unsigned*)hnxt + cg * 512 + growg * 4 + (up >> 1), p.u,
                                   __ATOMIC_RELAXED, __HIP_MEMORY_SCOPE_AGENT);
            }
        }
        if (s >= 1 && tid < 64) {
            // reduce 4 ksplit partials + bias; store out[row][512-s][cg]
            int rr = tid & 31, rss = tid >> 5;
            float val = sOd[rss][rr][0] + sOd[rss][rr][1] + sOd[rss][rr][2] + sOd[rss][rr][3] + ob;
            fu cv; cv.f = val;
            int growo = rg * 64 + rss * 32 + rr;
            __hip_atomic_store((unsigned*)(out + (size_t)growo * 65536 + (size_t)(512 - s) * 128 + cg),
                               cv.u, __ATOMIC_RELAXED, __HIP_MEMORY_SCOPE_AGENT);
        }
        if (s < 512) {
            __syncthreads();              // drains write-through h + out stores
            bar_arrive(ctr, g);
            bar_wait(ctr, (unsigned)(s + 1) * NWG);
        }
    }
}

// ---------------- launch ----------------
extern "C" void kernel_launch(void* const* d_in, const int* in_sizes, int n_in,
                              void* d_out, int out_size, void* d_ws, size_t ws_size,
                              hipStream_t stream) {
    (void)in_sizes; (void)n_in; (void)out_size; (void)ws_size;
    const float* x    = (const float*)d_in[0];
    const float* Wihe = (const float*)d_in[1];
    const float* Whhe = (const float*)d_in[2];
    const float* bihe = (const float*)d_in[3];
    const float* bhhe = (const float*)d_in[4];
    const float* Wihd = (const float*)d_in[5];
    const float* Whhd = (const float*)d_in[6];
    const float* bihd = (const float*)d_in[7];
    const float* bhhd = (const float*)d_in[8];
    const float* Wout = (const float*)d_in[9];
    const float* bout = (const float*)d_in[10];

    char* ws = (char*)d_ws;
    __bf16*   h0  = (__bf16*)(ws + O_H0);
    __bf16*   h1  = (__bf16*)(ws + O_H1);
    float*    h32 = (float*)(ws + O_H32);
    unsigned* ctr = (unsigned*)(ws + O_CTR);
    __bf16*   xbf = (__bf16*)(ws + O_XB);
    __bf16*   Weh = (__bf16*)(ws + O_WEH);
    __bf16*   Wex = (__bf16*)(ws + O_WEX);
    float*    be  = (float*)(ws + O_BE);
    __bf16*   Wd  = (__bf16*)(ws + O_WD);
    float*    bd  = (float*)(ws + O_BD);
    __bf16*   Wc  = (__bf16*)(ws + O_WC);
    __bf16*   Wob = (__bf16*)(ws + O_WOB);

    hipMemsetAsync(ws, 0, O_ZERO_END, stream);   // h0/h1/h32 + both sync blocks

    k_xcvt<<<4096, 256, 0, stream>>>(x, xbf, B_ * S_ * F_);
    k_pack_enc<<<128, 256, 0, stream>>>(Wihe, Whhe, bihe, bhhe, Weh, Wex, be);
    k_wcomb<<<384, 256, 0, stream>>>(Wihd, Wout, Wc);
    k_pack_dec<<<128, 256, 0, stream>>>(Whhd, Wc, Wihd, bihd, bhhd, bout, Wd, bd);
    k_woutb<<<512, 256, 0, stream>>>(Wout, Wob, F_ * L_);

    k_enc<<<NWG, 512, 0, stream>>>(xbf, Weh, Wex, be, h0, h1, h32, ctr);
    k_dec<<<NWG, 512, 0, stream>>>(Wd, bd, Wob, bout, h0, h1, h32, (float*)d_out,
                                   ctr + 1024);
}